// Round 3
// baseline (390.008 us; speedup 1.0000x reference)
//
#include <hip/hip_runtime.h>
#include <math.h>

#define PI_F 3.14159265358979323846f

constexpr int NM = 544;   // 32 kx-rows * 17 ky-cols of retained modes

// ---- workspace byte offsets (all 16B-aligned) ----
constexpr size_t OFF_F1 = 0;        // 128*34 floats  (col-DFT twiddle, /16384 folded)  17408 B
constexpr size_t OFF_F2 = 17408;    // 128*40 floats  (row-DFT twiddle, 20 slots/row)   20480 B
constexpr size_t OFF_G  = 37888;    // 32*128 float2  (inverse x-twiddle)               32768 B
constexpr size_t OFF_CT = 70656;    // 17*128 float2  (C2R cos/sin, weight folded)      17408 B
constexpr size_t OFF_XF = 88064;    // 1024*544 float2                                  4456448 B
constexpr size_t OFF_YS = 4544512;  // 1024*544 float2 (reduced, [ky*32+r] order)       4456448 B
constexpr size_t OFF_YP = 9000960;  // 4*1024*544 float2 partials; reused as Z

// ---------------- K0: twiddle tables ----------------
__global__ __launch_bounds__(256) void k_tab(float* __restrict__ F1, float* __restrict__ F2,
                                             float2* __restrict__ G, float2* __restrict__ CT) {
  const int t0 = blockIdx.x * 256 + threadIdx.x;
  const int N = gridDim.x * 256;
  const float inv = 1.0f / 16384.0f;
  for (int i = t0; i < 128 * 17; i += N) {
    int x = i / 17, r = i - 17 * x;
    float s, c; sincosf(-2.f * PI_F * (float)((x * r) & 127) / 128.f, &s, &c);
    F1[x * 34 + 2 * r] = c * inv; F1[x * 34 + 2 * r + 1] = s * inv;
  }
  for (int i = t0; i < 128 * 20; i += N) {
    int y = i / 20, k = i - 20 * y;
    if (k >= 17) { F2[y * 40 + 2 * k] = 0.f; F2[y * 40 + 2 * k + 1] = 0.f; }
    else {
      float s, c; sincosf(-2.f * PI_F * (float)((y * k) & 127) / 128.f, &s, &c);
      F2[y * 40 + 2 * k] = c; F2[y * 40 + 2 * k + 1] = s;
    }
  }
  for (int i = t0; i < 32 * 128; i += N) {
    int r = i >> 7, x = i & 127;
    int f = (r < 17) ? r : r + 96;
    float s, c; sincosf(2.f * PI_F * (float)((f * x) & 127) / 128.f, &s, &c);
    G[i] = make_float2(c, s);
  }
  for (int i = t0; i < 17 * 128; i += N) {
    int k = i >> 7;
    float w = k ? 2.f : 1.f;
    float s, c; sincosf(2.f * PI_F * (float)((k * (i & 127)) & 127) / 128.f, &s, &c);
    CT[i] = make_float2(w * c, w * s);
  }
}

// ---------------- K1: fused forward truncated DFT ----------------
// grid 1024 = b*128+t, block 256 (4 waves): phase1 x-split x2, phase2 ky-split x4
__global__ __launch_bounds__(256) void k_fwd(const float* __restrict__ X,
                                             const float* __restrict__ F1,
                                             const float* __restrict__ F2,
                                             float2* __restrict__ Xf) {
  __shared__ float2 tmp[128][17];   // column-DFT result [y][r]
  __shared__ float2 red[128][17];   // phase-1 partial from x-group 1
  const int tid = threadIdx.x;
  const int bt = blockIdx.x;
  const int y = tid & 127;
  const int g = tid >> 7;           // x-half

  // Phase 1: col[r][y] = sum_x X[x][y] * F1[x][r]. Lane = y; F1 scalar-loaded.
  float2 acc[17];
#pragma unroll
  for (int r = 0; r < 17; ++r) acc[r] = make_float2(0.f, 0.f);
  const float* xp = X + (size_t)bt * 16384 + y;
#pragma unroll 4
  for (int xi = 0; xi < 64; ++xi) {
    int x = g * 64 + xi;
    float v = xp[(size_t)x * 128];
    const float* f = F1 + x * 34;
#pragma unroll
    for (int r = 0; r < 17; ++r) {
      acc[r].x = fmaf(v, f[2 * r], acc[r].x);
      acc[r].y = fmaf(v, f[2 * r + 1], acc[r].y);
    }
  }
  if (g) {
#pragma unroll
    for (int r = 0; r < 17; ++r) red[y][r] = acc[r];
  }
  __syncthreads();
  if (!g) {
#pragma unroll
    for (int r = 0; r < 17; ++r) {
      float2 o = red[y][r];
      tmp[y][r] = make_float2(acc[r].x + o.x, acc[r].y + o.y);
    }
  }
  __syncthreads();

  // Phase 2: Xf[r][ky] = sum_y col[f(r)][y] e^{-2pi i ky y/128}.
  // wave w owns ky range [5w, 5w+5) (last: 2); lanes = (r:32, yh:2), shfl-reduced.
  const int lane = tid & 63;
  const int w = tid >> 6;
  const int r = lane & 31;
  const int yh = lane >> 5;
  const int r2 = (r < 17) ? r : 32 - r;      // conjugate source row
  const float sgn = (r < 17) ? 1.f : -1.f;
  const int ky0 = w * 5;
  const int nky = (w == 3) ? 2 : 5;
  float2 a2[5];
#pragma unroll
  for (int i = 0; i < 5; ++i) a2[i] = make_float2(0.f, 0.f);
  const float* f2b = F2 + 2 * ky0 + yh * 40;
  for (int yl = 0; yl < 64; ++yl) {
    float2 tv = tmp[2 * yl + yh][r2];
    float tvy = tv.y * sgn;
    const float* f = f2b + yl * 80;
#pragma unroll
    for (int i = 0; i < 5; ++i) {
      float cr = f[2 * i], ci = f[2 * i + 1];
      a2[i].x = fmaf(tv.x, cr, fmaf(-tvy, ci, a2[i].x));
      a2[i].y = fmaf(tv.x, ci, fmaf(tvy, cr, a2[i].y));
    }
  }
#pragma unroll
  for (int i = 0; i < 5; ++i) {
    a2[i].x += __shfl_xor(a2[i].x, 32);
    a2[i].y += __shfl_xor(a2[i].y, 32);
  }
  if (lane < 32) {
    for (int i = 0; i < nky; ++i)
      Xf[(size_t)bt * NM + r * 17 + ky0 + i] = a2[i];   // weight-native m = r*17+ky
  }
}

// ---------------- K2: skew-Hermitian channel mix ----------------
// grid 1024 = c(128) x q(8); q = chunk(4 of t) x bhalf(2 of b). block 576 = modes m.
__global__ __launch_bounds__(576) void k_mix(const float* __restrict__ Wre,
                                             const float* __restrict__ Wim,
                                             const float2* __restrict__ Xf,
                                             float2* __restrict__ Yp) {
  const int m = threadIdx.x;
  if (m >= NM) return;
  const int c = blockIdx.x & 127;
  const int q = blockIdx.x >> 7;
  const int chunk = q & 3;
  const int b0 = (q >> 2) * 4;
  float2 acc[4];
#pragma unroll
  for (int b = 0; b < 4; ++b) acc[b] = make_float2(0.f, 0.f);
  const int t0 = chunk * 32;
#pragma unroll 2
  for (int tt = 0; tt < 32; ++tt) {
    const int t = t0 + tt;
    float wr = Wre[(size_t)(c * 128 + t) * NM + m] - Wre[(size_t)(t * 128 + c) * NM + m];
    float wi = Wim[(size_t)(c * 128 + t) * NM + m] + Wim[(size_t)(t * 128 + c) * NM + m];
#pragma unroll
    for (int b = 0; b < 4; ++b) {
      float2 xv = Xf[(size_t)((b0 + b) * 128 + t) * NM + m];
      acc[b].x = fmaf(wr, xv.x, fmaf(-wi, xv.y, acc[b].x));
      acc[b].y = fmaf(wr, xv.y, fmaf(wi, xv.x, acc[b].y));
    }
  }
#pragma unroll
  for (int b = 0; b < 4; ++b)
    Yp[(size_t)chunk * 1024 * NM + (size_t)((b0 + b) * 128 + c) * NM + m] = acc[b];
}

// ---------------- K3: reduce 4 partials + permute m -> [ky*32+r] ----------------
__global__ __launch_bounds__(256) void k_red(const float2* __restrict__ Yp,
                                             float2* __restrict__ Ys) {
  int i = blockIdx.x * 256 + threadIdx.x;     // i < 1024*544
  if (i >= 1024 * NM) return;
  int bc = i / NM, m = i - bc * NM;
  int r = m / 17, ky = m - r * 17;
  float2 s = make_float2(0.f, 0.f);
#pragma unroll
  for (int ch = 0; ch < 4; ++ch) {
    float2 v = Yp[(size_t)ch * 1024 * NM + i];
    s.x += v.x; s.y += v.y;
  }
  Ys[(size_t)bc * NM + ky * 32 + r] = s;
}

// ---------------- K4: inverse row DFT (scalar Ys, per-lane G) ----------------
// grid 512, block 256 = 2 slices x 2 x-halves (wave each)
__global__ __launch_bounds__(256) void k_invB(const float* __restrict__ Ys,
                                              const float2* __restrict__ G,
                                              float2* __restrict__ Z) {
  const int tid = threadIdx.x;
  const int lane = tid & 63;
  const int bc = __builtin_amdgcn_readfirstlane(blockIdx.x * 2 + (tid >> 7));
  const int xh = __builtin_amdgcn_readfirstlane((tid >> 6) & 1);
  const int x = xh * 64 + lane;
  float2 g[32];
#pragma unroll
  for (int r = 0; r < 32; ++r) g[r] = G[r * 128 + x];
  const float* yb = Ys + (size_t)bc * (NM * 2);
  float2* zb = Z + (size_t)bc * (17 * 128) + x;
  for (int ky = 0; ky < 17; ++ky) {
    const float* yk = yb + ky * 64;      // 32 consecutive complex -> s_load
    float zr = 0.f, zi = 0.f;
#pragma unroll
    for (int r = 0; r < 32; ++r) {
      float ar = yk[2 * r], ai = yk[2 * r + 1];
      zr = fmaf(ar, g[r].x, fmaf(-ai, g[r].y, zr));
      zi = fmaf(ar, g[r].y, fmaf(ai, g[r].x, zi));
    }
    zb[ky * 128] = make_float2(zr, zi);  // Z[bc][ky][x], coalesced
  }
}

// ---------------- K5: C2R reconstruction (scalar Z, per-lane cos/sin) ----------------
// grid 1024 = (b,c), block 256: lanes = yy, waves split x halves
__global__ __launch_bounds__(256) void k_invC(const float* __restrict__ Z,
                                              const float2* __restrict__ CT,
                                              float* __restrict__ out) {
  const int tid = threadIdx.x;
  const int yy = tid & 127;
  const int xh = __builtin_amdgcn_readfirstlane(tid >> 7);
  const int bc = blockIdx.x;
  float2 ct[17];
#pragma unroll
  for (int k = 0; k < 17; ++k) ct[k] = CT[k * 128 + yy];
  const float* zb = Z + (size_t)bc * (17 * 128 * 2);
  float* op = out + (size_t)bc * 16384;
#pragma unroll 2
  for (int xi = 0; xi < 64; ++xi) {
    int x = xh * 64 + xi;
    const float* zp = zb + 2 * x;        // uniform address -> s_load per ky
    float s = 0.f;
#pragma unroll
    for (int k = 0; k < 17; ++k) {
      float zr = zp[k * 256], zi = zp[k * 256 + 1];
      s = fmaf(zr, ct[k].x, fmaf(-zi, ct[k].y, s));
    }
    op[x * 128 + yy] = s;                // coalesced 64 MB store
  }
}

extern "C" void kernel_launch(void* const* d_in, const int* in_sizes, int n_in,
                              void* d_out, int out_size, void* d_ws, size_t ws_size,
                              hipStream_t stream) {
  const float* X   = (const float*)d_in[0];
  const float* Wre = (const float*)d_in[1];
  const float* Wim = (const float*)d_in[2];
  float* out = (float*)d_out;

  char* ws = (char*)d_ws;
  float*  F1 = (float*)(ws + OFF_F1);
  float*  F2 = (float*)(ws + OFF_F2);
  float2* G  = (float2*)(ws + OFF_G);
  float2* CT = (float2*)(ws + OFF_CT);
  float2* Xf = (float2*)(ws + OFF_XF);
  float2* Ys = (float2*)(ws + OFF_YS);
  float2* Yp = (float2*)(ws + OFF_YP);
  float2* Z  = Yp;                        // Yp dead after k_red; reuse as Z

  k_tab <<<32, 256, 0, stream>>>(F1, F2, G, CT);
  k_fwd <<<1024, 256, 0, stream>>>(X, F1, F2, Xf);
  k_mix <<<1024, 576, 0, stream>>>(Wre, Wim, Xf, Yp);
  k_red <<<2176, 256, 0, stream>>>(Yp, Ys);
  k_invB<<<512, 256, 0, stream>>>((const float*)Ys, G, Z);
  k_invC<<<1024, 256, 0, stream>>>((const float*)Z, CT, out);
}

// Round 4
// 334.562 us; speedup vs baseline: 1.1657x; 1.1657x over previous
//
#include <hip/hip_runtime.h>
#include <math.h>

#define PI_F 3.14159265358979323846f

constexpr int NM = 544;   // 32 kx-rows * 17 ky-cols of retained modes

// ---- workspace byte offsets (all 16B-aligned) ----
constexpr size_t OFF_F1T = 0;        // 17*128 cplx (col-DFT twiddle F1T[r][x], /16384 folded) 17408 B
constexpr size_t OFF_F2  = 17408;    // 128*40 floats (row-DFT twiddle F2[y][k], 20 slots/row) 20480 B
constexpr size_t OFF_G   = 37888;    // 32*128 float2 (inverse x-twiddle G[r][x])              32768 B
constexpr size_t OFF_CT  = 70656;    // 17*128 float2 (C2R cos/sin, weight folded)            17408 B
constexpr size_t OFF_XF  = 88064;    // 1024*544 float2                                       4456448 B
constexpr size_t OFF_YS  = 4544512;  // 1024*544 float2 (reduced, [ky*32+r] order)            4456448 B
constexpr size_t OFF_YP  = 9000960;  // 4*1024*544 float2 partials; reused as Z (1024*17*128)

// ---------------- K0: twiddle tables ----------------
__global__ __launch_bounds__(256) void k_tab(float* __restrict__ F1T, float* __restrict__ F2,
                                             float2* __restrict__ G, float2* __restrict__ CT) {
  const int t0 = blockIdx.x * 256 + threadIdx.x;
  const int N = gridDim.x * 256;
  const float inv = 1.0f / 16384.0f;
  for (int i = t0; i < 17 * 128; i += N) {
    int r = i >> 7, x = i & 127;
    float s, c; sincosf(-2.f * PI_F * (float)((x * r) & 127) / 128.f, &s, &c);
    F1T[2 * i] = c * inv; F1T[2 * i + 1] = s * inv;
  }
  for (int i = t0; i < 128 * 20; i += N) {
    int y = i / 20, k = i - 20 * y;
    if (k >= 17) { F2[y * 40 + 2 * k] = 0.f; F2[y * 40 + 2 * k + 1] = 0.f; }
    else {
      float s, c; sincosf(-2.f * PI_F * (float)((y * k) & 127) / 128.f, &s, &c);
      F2[y * 40 + 2 * k] = c; F2[y * 40 + 2 * k + 1] = s;
    }
  }
  for (int i = t0; i < 32 * 128; i += N) {
    int r = i >> 7, x = i & 127;
    int f = (r < 17) ? r : r + 96;
    float s, c; sincosf(2.f * PI_F * (float)((f * x) & 127) / 128.f, &s, &c);
    G[i] = make_float2(c, s);
  }
  for (int i = t0; i < 17 * 128; i += N) {
    int k = i >> 7;
    float w = k ? 2.f : 1.f;
    float s, c; sincosf(2.f * PI_F * (float)((k * (i & 127)) & 127) / 128.f, &s, &c);
    CT[i] = make_float2(w * c, w * s);
  }
}

// ---------------- K1: fused forward truncated DFT ----------------
// grid 1024 = slice (b,t), block 256 = 4 waves.
// Wave w owns r-range {4w..4w+3} (+r=16 for w0) in phase 1 and the same ky-range in phase 2.
// Phase-1 twiddles: wave-uniform global s_loads. Phase-2 twiddles: contiguous LDS b128.
__global__ __launch_bounds__(256) void k_fwd(const float* __restrict__ X,
                                             const float* __restrict__ F1T,
                                             const float* __restrict__ F2G,
                                             float2* __restrict__ Xf) {
  __shared__ float tmpL[128 * 38];   // col-DFT result, row y: 19 cplx slots (r 0..16 used)
  __shared__ float f2s[128 * 40];    // F2 copy
  const int tid = threadIdx.x;
  const int bt = blockIdx.x;

  {  // stage F2 -> LDS (coalesced float4)
    const float4* src = (const float4*)F2G;
    float4* dst = (float4*)f2s;
    for (int i = tid; i < 1280; i += 256) dst[i] = src[i];
  }

  const int wid = __builtin_amdgcn_readfirstlane(tid >> 6);
  const int lane = tid & 63;
  const bool w0 = (wid == 0);
  const int r0 = wid * 4;

  // ---- Phase 1: tmp[y][r] = sum_x X[x][y] * F1T[r][x] ----
  for (int yh = 0; yh < 2; ++yh) {
    const int y = yh * 64 + lane;
    float2 acc[5];
#pragma unroll
    for (int i = 0; i < 5; ++i) acc[i] = make_float2(0.f, 0.f);
    const float* xp = X + (size_t)bt * 16384 + y;
    for (int xc = 0; xc < 32; ++xc) {
      const float* xq = xp + xc * 512;
      float v0 = xq[0], v1 = xq[128], v2 = xq[256], v3 = xq[384];
#pragma unroll
      for (int i = 0; i < 4; ++i) {
        const float* t = F1T + ((r0 + i) << 8) + (xc << 3);   // uniform -> s_load
        acc[i].x = fmaf(v0, t[0], acc[i].x); acc[i].y = fmaf(v0, t[1], acc[i].y);
        acc[i].x = fmaf(v1, t[2], acc[i].x); acc[i].y = fmaf(v1, t[3], acc[i].y);
        acc[i].x = fmaf(v2, t[4], acc[i].x); acc[i].y = fmaf(v2, t[5], acc[i].y);
        acc[i].x = fmaf(v3, t[6], acc[i].x); acc[i].y = fmaf(v3, t[7], acc[i].y);
      }
      if (w0) {
        const float* t = F1T + (16 << 8) + (xc << 3);
        acc[4].x = fmaf(v0, t[0], acc[4].x); acc[4].y = fmaf(v0, t[1], acc[4].y);
        acc[4].x = fmaf(v1, t[2], acc[4].x); acc[4].y = fmaf(v1, t[3], acc[4].y);
        acc[4].x = fmaf(v2, t[4], acc[4].x); acc[4].y = fmaf(v2, t[5], acc[4].y);
        acc[4].x = fmaf(v3, t[6], acc[4].x); acc[4].y = fmaf(v3, t[7], acc[4].y);
      }
    }
#pragma unroll
    for (int i = 0; i < 4; ++i) {
      tmpL[y * 38 + 2 * (r0 + i)]     = acc[i].x;
      tmpL[y * 38 + 2 * (r0 + i) + 1] = acc[i].y;
    }
    if (w0) { tmpL[y * 38 + 32] = acc[4].x; tmpL[y * 38 + 33] = acc[4].y; }
  }
  __syncthreads();

  // ---- Phase 2: Xf[r][ky] = sum_y tmp[y][f(r)] * e^{-2pi i ky y/128} ----
  const int r = lane & 31;
  const int yh = lane >> 5;
  const int r2 = (r < 17) ? r : 32 - r;
  const float sgn = (r < 17) ? 1.f : -1.f;
  const int ky0 = wid * 4;
  float2 a2[5];
#pragma unroll
  for (int i = 0; i < 5; ++i) a2[i] = make_float2(0.f, 0.f);
  const float* f2p = f2s + yh * 40 + 2 * ky0;   // 16B-aligned
  const float* tp  = tmpL + yh * 38 + 2 * r2;
  for (int yl = 0; yl < 64; ++yl) {
    float2 tv = *(const float2*)tp;
    float tx = tv.x, ts = tv.y * sgn;
    float4 c01 = *(const float4*)(f2p);
    float4 c23 = *(const float4*)(f2p + 4);
    a2[0].x = fmaf(tx, c01.x, fmaf(-ts, c01.y, a2[0].x));
    a2[0].y = fmaf(tx, c01.y, fmaf( ts, c01.x, a2[0].y));
    a2[1].x = fmaf(tx, c01.z, fmaf(-ts, c01.w, a2[1].x));
    a2[1].y = fmaf(tx, c01.w, fmaf( ts, c01.z, a2[1].y));
    a2[2].x = fmaf(tx, c23.x, fmaf(-ts, c23.y, a2[2].x));
    a2[2].y = fmaf(tx, c23.y, fmaf( ts, c23.x, a2[2].y));
    a2[3].x = fmaf(tx, c23.z, fmaf(-ts, c23.w, a2[3].x));
    a2[3].y = fmaf(tx, c23.w, fmaf( ts, c23.z, a2[3].y));
    if (w0) {
      float2 c4 = *(const float2*)(f2p + 32);   // ky = 16
      a2[4].x = fmaf(tx, c4.x, fmaf(-ts, c4.y, a2[4].x));
      a2[4].y = fmaf(tx, c4.y, fmaf( ts, c4.x, a2[4].y));
    }
    f2p += 80; tp += 76;
  }
#pragma unroll
  for (int i = 0; i < 5; ++i) {
    a2[i].x += __shfl_xor(a2[i].x, 32);
    a2[i].y += __shfl_xor(a2[i].y, 32);
  }
  if (lane < 32) {
    float2* xo = Xf + (size_t)bt * NM + r * 17 + ky0;
#pragma unroll
    for (int i = 0; i < 4; ++i) xo[i] = a2[i];
    if (w0) xo[16] = a2[4];     // ky0==0 here, so r*17+16
  }
}

// ---------------- K2: skew-Hermitian channel mix ----------------
// grid 1024 = c(128) x q(8); q = chunk(4 of t) x bhalf(2 of b). block 576 = modes m.
__global__ __launch_bounds__(576) void k_mix(const float* __restrict__ Wre,
                                             const float* __restrict__ Wim,
                                             const float2* __restrict__ Xf,
                                             float2* __restrict__ Yp) {
  const int m = threadIdx.x;
  if (m >= NM) return;
  const int c = blockIdx.x & 127;
  const int q = blockIdx.x >> 7;
  const int chunk = q & 3;
  const int b0 = (q >> 2) * 4;
  float2 acc[4];
#pragma unroll
  for (int b = 0; b < 4; ++b) acc[b] = make_float2(0.f, 0.f);
  const int t0 = chunk * 32;
#pragma unroll 2
  for (int tt = 0; tt < 32; ++tt) {
    const int t = t0 + tt;
    float wr = Wre[(size_t)(c * 128 + t) * NM + m] - Wre[(size_t)(t * 128 + c) * NM + m];
    float wi = Wim[(size_t)(c * 128 + t) * NM + m] + Wim[(size_t)(t * 128 + c) * NM + m];
#pragma unroll
    for (int b = 0; b < 4; ++b) {
      float2 xv = Xf[(size_t)((b0 + b) * 128 + t) * NM + m];
      acc[b].x = fmaf(wr, xv.x, fmaf(-wi, xv.y, acc[b].x));
      acc[b].y = fmaf(wr, xv.y, fmaf(wi, xv.x, acc[b].y));
    }
  }
#pragma unroll
  for (int b = 0; b < 4; ++b)
    Yp[(size_t)chunk * 1024 * NM + (size_t)((b0 + b) * 128 + c) * NM + m] = acc[b];
}

// ---------------- K3: reduce 4 partials + permute m -> [ky*32+r] ----------------
__global__ __launch_bounds__(256) void k_red(const float2* __restrict__ Yp,
                                             float2* __restrict__ Ys) {
  int i = blockIdx.x * 256 + threadIdx.x;     // i < 1024*544
  if (i >= 1024 * NM) return;
  int bc = i / NM, m = i - bc * NM;
  int r = m / 17, ky = m - r * 17;
  float2 s = make_float2(0.f, 0.f);
#pragma unroll
  for (int ch = 0; ch < 4; ++ch) {
    float2 v = Yp[(size_t)ch * 1024 * NM + i];
    s.x += v.x; s.y += v.y;
  }
  Ys[(size_t)bc * NM + ky * 32 + r] = s;
}

// ---------------- K4: inverse row DFT ----------------
// grid 1024 = slice (b,c), block 256 = (x': 64 lanes, xh: 2, ky-parity p: 2)
__global__ __launch_bounds__(256) void k_invB(const float* __restrict__ Ys,
                                              const float2* __restrict__ G,
                                              float2* __restrict__ Z) {
  const int tid = threadIdx.x;
  const int lane = tid & 63;
  const int xh = __builtin_amdgcn_readfirstlane((tid >> 6) & 1);
  const int p  = __builtin_amdgcn_readfirstlane(tid >> 7);
  const int x = xh * 64 + lane;
  const int bc = blockIdx.x;
  float2 g[32];
#pragma unroll
  for (int r = 0; r < 32; ++r) g[r] = G[r * 128 + x];
  const float* yb = Ys + (size_t)bc * (NM * 2);
  float2* zb = Z + (size_t)bc * (17 * 128) + x;
#pragma unroll
  for (int i = 0; i < 8; ++i) {
    const int ky = 2 * i + p;
    const float* yk = yb + ky * 64;     // uniform -> s_load
    float zr = 0.f, zi = 0.f;
#pragma unroll
    for (int r = 0; r < 32; ++r) {
      float ar = yk[2 * r], ai = yk[2 * r + 1];
      zr = fmaf(ar, g[r].x, fmaf(-ai, g[r].y, zr));
      zi = fmaf(ar, g[r].y, fmaf(ai, g[r].x, zi));
    }
    zb[ky * 128] = make_float2(zr, zi);
  }
  if (p == 0) {
    const float* yk = yb + 16 * 64;
    float zr = 0.f, zi = 0.f;
#pragma unroll
    for (int r = 0; r < 32; ++r) {
      float ar = yk[2 * r], ai = yk[2 * r + 1];
      zr = fmaf(ar, g[r].x, fmaf(-ai, g[r].y, zr));
      zi = fmaf(ar, g[r].y, fmaf(ai, g[r].x, zi));
    }
    zb[16 * 128] = make_float2(zr, zi);
  }
}

// ---------------- K5: C2R reconstruction (scalar Z, per-lane cos/sin) ----------------
// grid 1024 = (b,c), block 256: lanes = yy, waves split x halves
__global__ __launch_bounds__(256) void k_invC(const float* __restrict__ Z,
                                              const float2* __restrict__ CT,
                                              float* __restrict__ out) {
  const int tid = threadIdx.x;
  const int yy = tid & 127;
  const int xh = __builtin_amdgcn_readfirstlane(tid >> 7);
  const int bc = blockIdx.x;
  float2 ct[17];
#pragma unroll
  for (int k = 0; k < 17; ++k) ct[k] = CT[k * 128 + yy];
  const float* zb = Z + (size_t)bc * (17 * 128 * 2);
  float* op = out + (size_t)bc * 16384;
#pragma unroll 2
  for (int xi = 0; xi < 64; ++xi) {
    int x = xh * 64 + xi;
    const float* zp = zb + 2 * x;        // uniform -> s_load per ky
    float s = 0.f;
#pragma unroll
    for (int k = 0; k < 17; ++k) {
      float zr = zp[k * 256], zi = zp[k * 256 + 1];
      s = fmaf(zr, ct[k].x, fmaf(-zi, ct[k].y, s));
    }
    op[x * 128 + yy] = s;                // coalesced 64 MB store
  }
}

extern "C" void kernel_launch(void* const* d_in, const int* in_sizes, int n_in,
                              void* d_out, int out_size, void* d_ws, size_t ws_size,
                              hipStream_t stream) {
  const float* X   = (const float*)d_in[0];
  const float* Wre = (const float*)d_in[1];
  const float* Wim = (const float*)d_in[2];
  float* out = (float*)d_out;

  char* ws = (char*)d_ws;
  float*  F1T = (float*)(ws + OFF_F1T);
  float*  F2  = (float*)(ws + OFF_F2);
  float2* G   = (float2*)(ws + OFF_G);
  float2* CT  = (float2*)(ws + OFF_CT);
  float2* Xf  = (float2*)(ws + OFF_XF);
  float2* Ys  = (float2*)(ws + OFF_YS);
  float2* Yp  = (float2*)(ws + OFF_YP);
  float2* Z   = Yp;                       // Yp dead after k_red; reuse as Z

  k_tab <<<32, 256, 0, stream>>>(F1T, F2, G, CT);
  k_fwd <<<1024, 256, 0, stream>>>(X, F1T, F2, Xf);
  k_mix <<<1024, 576, 0, stream>>>(Wre, Wim, Xf, Yp);
  k_red <<<2176, 256, 0, stream>>>(Yp, Ys);
  k_invB<<<1024, 256, 0, stream>>>((const float*)Ys, G, Z);
  k_invC<<<1024, 256, 0, stream>>>((const float*)Z, CT, out);
}